// Round 1
// baseline (243.080 us; speedup 1.0000x reference)
//
#include <hip/hip_runtime.h>
#include <hip/hip_bf16.h>

#define LL 9216            // 96*96
#define TOT 36864          // 4*LL
#define CHK 144
#define NSEG 144
#define EPS_N 5e-5f

typedef __bf16 bf16x8 __attribute__((ext_vector_type(8)));
typedef float f32x4 __attribute__((ext_vector_type(4)));

__device__ __forceinline__ float dot4(float4 a, float4 b) {
    return a.x*b.x + a.y*b.y + a.z*b.z + a.w*b.w;
}
__device__ __forceinline__ unsigned short f2bf(float f) {
    __hip_bfloat16 h = __float2bfloat16(f);
    return *reinterpret_cast<unsigned short*>(&h);
}
__device__ __forceinline__ float bf2f(unsigned short u) {
    return __uint_as_float(((unsigned int)u) << 16);
}

// ---------------- K1: xe conv + LSH codes + bf16 xeb/xnb + weight prep -----------
// blocks 0..287: conv 8x8 tile + codes; blocks 288..575: weight prep. 46 KB LDS.
__global__ __launch_bounds__(256) void k_front(
    const float* __restrict__ x, const float* __restrict__ wm,
    const float* __restrict__ bm, const float* __restrict__ rot,
    unsigned short* __restrict__ xeb, unsigned short* __restrict__ xnb,
    unsigned char* __restrict__ codes,
    const float* __restrict__ fc1w, const float* __restrict__ fc2w,
    const float* __restrict__ wa, const float* __restrict__ wf,
    unsigned short* __restrict__ w1bf, unsigned short* __restrict__ w2bf,
    unsigned short* __restrict__ wpack)
{
    int tid = threadIdx.x;
    if (blockIdx.x >= 288) {   // ---- weight prep ----
        int i = (blockIdx.x - 288) * 256 + tid;
        if (i < 144 * 64) w1bf[i] = f2bf(fc1w[i]);
        if (i < 144 * 160) {
            int r = i / 160, c = i - r * 160;
            w2bf[i] = (c < 144) ? f2bf(fc2w[r * 144 + c]) : 0;
        }
        if (i < 128 * 576) {
            int o = i / 576, kk = i - o * 576;
            int dydx = kk >> 6, c = kk & 63;
            const float* src = (o < 64) ? wa : wf;
            wpack[i] = f2bf(src[(o & 63) * 576 + c * 9 + dydx]);
        }
        return;
    }
    __shared__ float xl[6400];       // [64][10][10] halo tile (25.6 KB)
    __shared__ float rotT[4096];     // [h*64+i][16]          (16 KB)
    __shared__ float xsp[64 * 20];   // [pos][ch pad20]       (5 KB)
    int b = blockIdx.x;
    int n = b / 144, tile = b % 144;
    int ty0 = (tile / 12) * 8, tx0 = (tile % 12) * 8;
    for (int li = tid; li < 6400; li += 256) {
        int c = li / 100, s = li % 100;
        int yy = s / 10, xx = s % 10;
        int gy = ty0 + yy - 1, gx = tx0 + xx - 1;
        float v = 0.f;
        if ((unsigned)gy < 96u && (unsigned)gx < 96u)
            v = x[((n * 64 + c) * 96 + gy) * 96 + gx];
        xl[li] = v;
    }
    for (int e = tid; e < 4096; e += 256) {
        int f = e >> 8, r = e & 255;
        rotT[r * 16 + f] = rot[f * 256 + r];   // rot is (16,4,64)
    }
    __syncthreads();
    int p = tid & 63, og = tid >> 6;
    int row = p >> 3, col = p & 7;
    int ogs = __builtin_amdgcn_readfirstlane(og);   // wave-uniform -> s_load path
    const float* wb = wm + (size_t)ogs * 4 * 576;
    float acc0 = 0.f, acc1 = 0.f, acc2 = 0.f, acc3 = 0.f;
    for (int c = 0; c < 64; ++c) {
        float xp[9];
        int base = c * 100 + row * 10 + col;
        #pragma unroll
        for (int dy = 0; dy < 3; ++dy)
            #pragma unroll
            for (int dx = 0; dx < 3; ++dx)
                xp[dy * 3 + dx] = xl[base + dy * 10 + dx];
        const float* w0 = wb + c * 9;
        #pragma unroll
        for (int u = 0; u < 9; ++u) {
            acc0 += w0[u]        * xp[u];
            acc1 += w0[576 + u]  * xp[u];
            acc2 += w0[1152 + u] * xp[u];
            acc3 += w0[1728 + u] * xp[u];
        }
    }
    int o = ogs * 4;
    float v0 = acc0 + bm[o + 0]; v0 = v0 > 0.f ? v0 : 0.f;
    float v1 = acc1 + bm[o + 1]; v1 = v1 > 0.f ? v1 : 0.f;
    float v2 = acc2 + bm[o + 2]; v2 = v2 > 0.f ? v2 : 0.f;
    float v3 = acc3 + bm[o + 3]; v3 = v3 > 0.f ? v3 : 0.f;
    size_t t = (size_t)n * LL + (ty0 + row) * 96 + tx0 + col;
    unsigned short pk[4] = {f2bf(v0), f2bf(v1), f2bf(v2), f2bf(v3)};
    *(uint2*)(xeb + t * 16 + o) = *(uint2*)pk;
    *(float4*)(xsp + p * 20 + o) = make_float4(v0, v1, v2, v3);
    __syncthreads();
    // ---- codes phase: thread = (pos = tid&63, h = tid>>6) ----
    int pos = tid & 63, h = tid >> 6;
    int prow = pos >> 3, pcol = pos & 7;
    size_t tc = (size_t)n * LL + (ty0 + prow) * 96 + tx0 + pcol;
    float4 q0 = *(float4*)(xsp + pos * 20 + 0);
    float4 q1 = *(float4*)(xsp + pos * 20 + 4);
    float4 q2 = *(float4*)(xsp + pos * 20 + 8);
    float4 q3 = *(float4*)(xsp + pos * 20 + 12);
    if (h == 0) {
        float nn = dot4(q0,q0) + dot4(q1,q1) + dot4(q2,q2) + dot4(q3,q3);
        float s = fmaxf(sqrtf(nn), EPS_N);
        float inv = 1.f / s;
        unsigned short pn[16];
        pn[0]=f2bf(q0.x*inv);  pn[1]=f2bf(q0.y*inv);  pn[2]=f2bf(q0.z*inv);  pn[3]=f2bf(q0.w*inv);
        pn[4]=f2bf(q1.x*inv);  pn[5]=f2bf(q1.y*inv);  pn[6]=f2bf(q1.z*inv);  pn[7]=f2bf(q1.w*inv);
        pn[8]=f2bf(q2.x*inv);  pn[9]=f2bf(q2.y*inv);  pn[10]=f2bf(q2.z*inv); pn[11]=f2bf(q2.w*inv);
        pn[12]=f2bf(q3.x*inv); pn[13]=f2bf(q3.y*inv); pn[14]=f2bf(q3.z*inv); pn[15]=f2bf(q3.w*inv);
        *(uint4*)(xnb + tc * 16)     = ((uint4*)pn)[0];
        *(uint4*)(xnb + tc * 16 + 8) = ((uint4*)pn)[1];
    }
    float best = -1e30f; int bi = 0;
    const float* rp = rotT + h * 1024;
    for (int i = 0; i < 64; ++i) {
        const float4* r4 = (const float4*)(rp + i * 16);
        float v = dot4(q0, r4[0]) + dot4(q1, r4[1]) + dot4(q2, r4[2]) + dot4(q3, r4[3]);
        if (v > best) { best = v; bi = i; }   // strict > = first max (jnp.argmax)
    }
    codes[(size_t)n * TOT + h * LL + (tc - (size_t)n * LL)] = (unsigned char)(h * 64 + bi);
}

// ---------------- K2: ye/fe conv bf16 MFMA + fused fc1/relu/fc2 + fused hist -----
__global__ __launch_bounds__(256) void k_convbf_fc(
    const float* __restrict__ x, const unsigned short* __restrict__ wpack,
    const float* __restrict__ ba, const float* __restrict__ bfb,
    const unsigned short* __restrict__ w1bf, const float* __restrict__ fc1_b,
    const unsigned short* __restrict__ w2bf, const float* __restrict__ fc2_b,
    unsigned short* __restrict__ yeb, unsigned short* __restrict__ re2b,
    const unsigned char* __restrict__ codes, int* __restrict__ hist)
{
    __shared__ unsigned short xt[3 * 50 * 72];   // input halo strip, ch-inner
    __shared__ unsigned short fet[48 * 72];      // fe tile [pos][ch]
    __shared__ unsigned short hb [48 * 168];     // hid [pos][m pad160]
    __shared__ int lh[256];
    int tid = threadIdx.x;
    if (blockIdx.x >= 384) {   // ---- histogram branch ----
        int b2 = blockIdx.x - 384;
        int n = b2 / NSEG, seg = b2 % NSEG;
        lh[tid] = 0;
        __syncthreads();
        int code = codes[(size_t)n * TOT + seg * 256 + tid];
        atomicAdd(&lh[code], 1);
        __syncthreads();
        hist[((size_t)n * 256 + tid) * NSEG + seg] = lh[tid];
        return;
    }
    int b = blockIdx.x;
    int n = b / 192, rem = b % 192;
    int y = rem >> 1, strip = rem & 1;
    int x0 = strip * 48;
    for (int e = tid; e < 9600; e += 256) {
        int r = e / 3200, r2 = e - r * 3200;
        int c = r2 / 50, j = r2 - c * 50;
        int gy = y - 1 + r, gx = x0 - 1 + j;
        float v = 0.f;
        if ((unsigned)gy < 96u && (unsigned)gx < 96u)
            v = x[((n * 64 + c) * 96 + gy) * 96 + gx];
        xt[(r * 50 + j) * 72 + c] = f2bf(v);
    }
    for (int e = tid; e < 384; e += 256) {       // hb K-pad zero (cols 144..159)
        int r = e >> 3, pq = e & 7;
        *(unsigned int*)(hb + r * 168 + 144 + pq * 2) = 0;
    }
    __syncthreads();
    int wave = tid >> 6, lane = tid & 63;
    int n16 = lane & 15, quad = lane >> 4;
    f32x4 acc[2][3];
    #pragma unroll
    for (int mi = 0; mi < 2; ++mi)
        #pragma unroll
        for (int nt = 0; nt < 3; ++nt) acc[mi][nt] = (f32x4){0.f, 0.f, 0.f, 0.f};
    #pragma unroll
    for (int s = 0; s < 18; ++s) {
        int dydx = s >> 1, half = s & 1;
        int dy = dydx / 3, dxm = dydx - dy * 3;
        bf16x8 B[3];
        #pragma unroll
        for (int nt = 0; nt < 3; ++nt) {
            int j = nt * 16 + n16 + dxm;
            B[nt] = *(bf16x8*)(xt + (dy * 50 + j) * 72 + half * 32 + quad * 8);
        }
        #pragma unroll
        for (int mi = 0; mi < 2; ++mi) {
            int o = (wave * 2 + mi) * 16 + n16;
            bf16x8 A = *(const bf16x8*)(wpack + o * 576 + dydx * 64 + half * 32 + quad * 8);
            #pragma unroll
            for (int nt = 0; nt < 3; ++nt)
                acc[mi][nt] = __builtin_amdgcn_mfma_f32_16x16x32_bf16(A, B[nt], acc[mi][nt], 0, 0, 0);
        }
    }
    #pragma unroll
    for (int mi = 0; mi < 2; ++mi) {
        int mt = wave * 2 + mi;
        int obase = mt * 16 + quad * 4;          // 0..124, multiple of 4
        float4 b4 = (mt < 4) ? *(const float4*)(ba + obase)
                             : *(const float4*)(bfb + obase - 64);
        #pragma unroll
        for (int nt = 0; nt < 3; ++nt) {
            int j = nt * 16 + n16;               // local position 0..47
            unsigned short pk[4];
            float v0 = acc[mi][nt][0] + b4.x; pk[0] = f2bf(v0 > 0.f ? v0 : 0.f);
            float v1 = acc[mi][nt][1] + b4.y; pk[1] = f2bf(v1 > 0.f ? v1 : 0.f);
            float v2 = acc[mi][nt][2] + b4.z; pk[2] = f2bf(v2 > 0.f ? v2 : 0.f);
            float v3 = acc[mi][nt][3] + b4.w; pk[3] = f2bf(v3 > 0.f ? v3 : 0.f);
            if (mt < 4) {
                size_t t = (size_t)n * LL + y * 96 + x0 + j;
                *(uint2*)(yeb + t * 64 + obase) = *(uint2*)pk;
            } else {
                *(uint2*)(fet + j * 72 + (obase - 64)) = *(uint2*)pk;
            }
        }
    }
    __syncthreads();
    size_t R0 = (size_t)n * LL + y * 96 + x0;
    // GEMM1: hid = relu(fe @ w1^T + b1)
    for (int nt = wave; nt < 9; nt += 4) {
        int bn = nt * 16 + n16;
        bf16x8 b0 = *(const bf16x8*)(w1bf + bn * 64 + quad * 8);
        bf16x8 b1 = *(const bf16x8*)(w1bf + bn * 64 + 32 + quad * 8);
        float bb = fc1_b[bn];
        #pragma unroll
        for (int m = 0; m < 3; ++m) {
            int arow = m * 16 + n16;
            bf16x8 a0 = *(bf16x8*)(fet + arow * 72 + quad * 8);
            bf16x8 a1 = *(bf16x8*)(fet + arow * 72 + 32 + quad * 8);
            f32x4 c2 = {0.f, 0.f, 0.f, 0.f};
            c2 = __builtin_amdgcn_mfma_f32_16x16x32_bf16(a0, b0, c2, 0, 0, 0);
            c2 = __builtin_amdgcn_mfma_f32_16x16x32_bf16(a1, b1, c2, 0, 0, 0);
            #pragma unroll
            for (int r = 0; r < 4; ++r) {
                float v = c2[r] + bb;
                hb[(m * 16 + quad * 4 + r) * 168 + bn] = f2bf(v > 0.f ? v : 0.f);
            }
        }
    }
    __syncthreads();
    // GEMM2: re2 = hid @ w2^T + b2 (K=160)
    for (int nt = wave; nt < 9; nt += 4) {
        int bn = nt * 16 + n16;
        bf16x8 wv2[5];
        #pragma unroll
        for (int kk = 0; kk < 5; ++kk)
            wv2[kk] = *(const bf16x8*)(w2bf + bn * 160 + kk * 32 + quad * 8);
        float bb = fc2_b[bn];
        #pragma unroll
        for (int m = 0; m < 3; ++m) {
            int arow = m * 16 + n16;
            f32x4 c2 = {0.f, 0.f, 0.f, 0.f};
            #pragma unroll
            for (int kk = 0; kk < 5; ++kk) {
                bf16x8 a = *(bf16x8*)(hb + arow * 168 + kk * 32 + quad * 8);
                c2 = __builtin_amdgcn_mfma_f32_16x16x32_bf16(a, wv2[kk], c2, 0, 0, 0);
            }
            #pragma unroll
            for (int r = 0; r < 4; ++r)
                re2b[(R0 + m * 16 + quad * 4 + r) * 144 + bn] = f2bf(c2[r] + bb);
        }
    }
}

// ---------------- K3: counting sort scan + place --------------------------------
__global__ void k_scan(int* __restrict__ hist)
{
    __shared__ int sc[256];
    int n = blockIdx.x, bin = threadIdx.x;
    int* hp = hist + ((size_t)n * 256 + bin) * NSEG;
    int4 buf[36];
    int4* hp4 = (int4*)hp;
    #pragma unroll
    for (int q = 0; q < 36; ++q) buf[q] = hp4[q];
    int running = 0;
    #pragma unroll
    for (int q = 0; q < 36; ++q) {
        int t0 = buf[q].x; buf[q].x = running; running += t0;
        int t1 = buf[q].y; buf[q].y = running; running += t1;
        int t2 = buf[q].z; buf[q].z = running; running += t2;
        int t3 = buf[q].w; buf[q].w = running; running += t3;
    }
    sc[bin] = running;
    __syncthreads();
    for (int off = 1; off < 256; off <<= 1) {
        int v = sc[bin];
        int u = (bin >= off) ? sc[bin - off] : 0;
        __syncthreads();
        sc[bin] = v + u;
        __syncthreads();
    }
    int bs = sc[bin] - running;   // exclusive prefix over bins
    #pragma unroll
    for (int q = 0; q < 36; ++q) {
        buf[q].x += bs; buf[q].y += bs; buf[q].z += bs; buf[q].w += bs;
        hp4[q] = buf[q];
    }
}

__global__ __launch_bounds__(256) void k_place(
    const unsigned char* __restrict__ codes, const int* __restrict__ hist,
    int* __restrict__ idx)
{
    __shared__ unsigned char cl[256];
    int b = blockIdx.x, n = b / NSEG, seg = b % NSEG;
    int tid = threadIdx.x;
    int my = codes[(size_t)n * TOT + seg * 256 + tid];
    cl[tid] = (unsigned char)my;
    __syncthreads();
    int rank = 0;
    for (int j = 0; j < tid; ++j) rank += (cl[j] == my);
    int pos = hist[((size_t)n * 256 + my) * NSEG + seg] + rank;
    idx[(size_t)n * TOT + pos] = seg * 256 + tid;
}

// ---------------- K4: bucketed attention — barrier-free wave-split --------------
// R11 rewrite. Old version: 2 barriers/tile x 9 tiles locked 4 waves together at
// 2 blocks/CU -> MfmaUtil 3.8%, VALUBusy 24%, pure latency-bind, plus 4.95M
// bank-conflict cycles from the ushort yat scatter. Now each wave owns query
// tiles {wv, wv+4, (+8 for wv==0)} end-to-end: QK, softmax (alpha/l in regs),
// P spill to a PRIVATE LDS slice, and PV over all 64 channels. The only
// __syncthreads is after t_arr staging. V^T lives in per-wave swizzled slices
// (XOR block swizzle: writes 2-way max, b128 reads uniform). Q/K/fc fragments
// gather straight from global; next tile is register-prefetched (2x unroll).
__global__ __launch_bounds__(256, 2) void k_attn(
    const unsigned short* __restrict__ xeb, const unsigned short* __restrict__ xnb,
    const unsigned short* __restrict__ yeb, const unsigned short* __restrict__ re2b,
    const int* __restrict__ idx,
    unsigned short* __restrict__ ret, float* __restrict__ bsc)
{
    __shared__ __align__(16) unsigned short Vt[4][64 * 64]; // per-wave V^T [c][jslot] swizzled (32 KB)
    __shared__ __align__(16) unsigned short Pw[4][48 * 56]; // per-wave P [rowl][jcol] (21 KB)
    __shared__ __align__(16) unsigned short t_arr[432];

    int b = blockIdx.x;
    int n = b >> 8, rem = b & 255;
    int h = rem >> 6, k = rem & 63;
    int tid = threadIdx.x;
    int lane = tid & 63, wv = tid >> 6;
    int n16 = lane & 15, quad = lane >> 4;
    int nmt = (wv == 0) ? 3 : 2;                 // query tiles owned: {wv, wv+4, wv==0? 8}

    for (int r = tid; r < 432; r += 256) {
        int region = r / 144, i = r - region * 144;
        int dk = (region == 0) ? 0 : (region == 1 ? -1 : 1);
        int ck = (k + dk + 64) & 63;
        t_arr[r] = (unsigned short)(idx[(size_t)n * TOT + h * LL + ck * CHK + i] - h * LL);
    }
    __syncthreads();                             // the ONLY block-wide barrier

    unsigned short* Vw = &Vt[wv][0];
    unsigned short* Pp = &Pw[wv][0];
    const size_t nL = (size_t)n * LL;

    // zero-fill swizzled pad slots j=48..63 once (PV kk=1 quads 2,3 read them;
    // A side is zero there but NaN-pattern garbage in B would poison the MFMA)
    #pragma unroll
    for (int e = 0; e < 8; ++e) {
        int i2 = e * 64 + lane;
        int c = i2 >> 3, j = 48 + (i2 & 7) * 2;
        int bp = ((j >> 3) ^ (c >> 3) ^ (((c >> 2) & 1) << 2)) & 7;
        *(unsigned int*)(Vw + c * 64 + bp * 8 + (j & 7)) = 0;
    }

    // query A-fragments: K=16 real, padded to 32 via zero quads>=2
    bf16x8 afrag[3] = {};
    #pragma unroll
    for (int mi = 0; mi < 3; ++mi)
        if (mi < nmt && quad < 2)
            afrag[mi] = *(const bf16x8*)(xeb + (nL + t_arr[(wv + mi * 4) * 16 + n16]) * 16 + quad * 8);

    f32x4 acc[3][4];                             // [mi][ct]: rows mi, channels ct*16+n16
    float rm[3][4], rl[3][4];
    #pragma unroll
    for (int mi = 0; mi < 3; ++mi) {
        #pragma unroll
        for (int ct = 0; ct < 4; ++ct) acc[mi][ct] = (f32x4){0.f, 0.f, 0.f, 0.f};
        #pragma unroll
        for (int r = 0; r < 4; ++r) { rm[mi][r] = -1e30f; rl[mi][r] = 0.f; }
    }

    int su = lane & 7, sp = lane >> 3;           // V staging: channel chunk su, j-pair base sp

    uint4 vaA[3], vbA[3], vaB[3], vbB[3];
    bf16x8 bfA[3] = {}, bfB[3] = {};
    ushort4 fA[3][3], fB[3][3];

// issue tile TT's global loads into the given register set (no LDS writes)
#define ATTN_LOAD(TT, VA, VB, BF, FF) do {                                           \
    int rr_ = (TT) * 48;                                                             \
    _Pragma("unroll")                                                                \
    for (int il_ = 0; il_ < 3; ++il_) {                                              \
        unsigned int tt_ = *(const unsigned int*)(t_arr + rr_ + (il_ * 8 + sp) * 2); \
        VA[il_] = *(const uint4*)(yeb + (nL + (tt_ & 0xffffu)) * 64 + su * 8);       \
        VB[il_] = *(const uint4*)(yeb + (nL + (tt_ >> 16)) * 64 + su * 8);           \
    }                                                                                \
    int tk0_ = t_arr[rr_ + n16], tk1_ = t_arr[rr_ + 16 + n16], tk2_ = t_arr[rr_ + 32 + n16]; \
    if (quad < 2) {                                                                  \
        BF[0] = *(const bf16x8*)(xnb + (nL + tk0_) * 16 + quad * 8);                 \
        BF[1] = *(const bf16x8*)(xnb + (nL + tk1_) * 16 + quad * 8);                 \
        BF[2] = *(const bf16x8*)(xnb + (nL + tk2_) * 16 + quad * 8);                 \
    }                                                                                \
    _Pragma("unroll")                                                                \
    for (int mq_ = 0; mq_ < 3; ++mq_) {                                              \
        if (mq_ >= nmt) continue;                                                    \
        int qc_ = (wv + mq_ * 4) * 16 + quad * 4;                                    \
        FF[mq_][0] = *(const ushort4*)(re2b + (nL + tk0_) * 144 + qc_);              \
        FF[mq_][1] = *(const ushort4*)(re2b + (nL + tk1_) * 144 + qc_);              \
        FF[mq_][2] = *(const ushort4*)(re2b + (nL + tk2_) * 144 + qc_);              \
    }                                                                                \
} while (0)

// one key-tile iteration: spill V regs -> own slice, prefetch TT+1, QK+softmax, PV
#define ATTN_ITER(TT, VA, VB, BF, FF, NVA, NVB, NBF, NFF) do {                       \
    _Pragma("unroll")                                                                \
    for (int it_ = 0; it_ < 3; ++it_) {                                              \
        int j0_ = (it_ * 8 + sp) * 2;                                                \
        const unsigned short* pa_ = (const unsigned short*)&VA[it_];                 \
        const unsigned short* pb_ = (const unsigned short*)&VB[it_];                 \
        int B0_ = j0_ >> 3, jlo_ = j0_ & 7;                                          \
        _Pragma("unroll")                                                            \
        for (int ci_ = 0; ci_ < 8; ++ci_) {                                          \
            int c_ = su * 8 + ci_;                                                   \
            int bp_ = (B0_ ^ (c_ >> 3) ^ (((c_ >> 2) & 1) << 2)) & 7;                \
            *(unsigned int*)(Vw + c_ * 64 + bp_ * 8 + jlo_) =                        \
                (unsigned int)pa_[ci_] | ((unsigned int)pb_[ci_] << 16);             \
        }                                                                            \
    }                                                                                \
    if ((TT) < 8) ATTN_LOAD((TT) + 1, NVA, NVB, NBF, NFF);                           \
    _Pragma("unroll")                                                                \
    for (int mi_ = 0; mi_ < 3; ++mi_) {                                              \
        if (mi_ >= nmt) continue;                                                    \
        f32x4 c0_ = {bf2f(FF[mi_][0].x), bf2f(FF[mi_][0].y), bf2f(FF[mi_][0].z), bf2f(FF[mi_][0].w)}; \
        f32x4 c1_ = {bf2f(FF[mi_][1].x), bf2f(FF[mi_][1].y), bf2f(FF[mi_][1].z), bf2f(FF[mi_][1].w)}; \
        f32x4 c2_ = {bf2f(FF[mi_][2].x), bf2f(FF[mi_][2].y), bf2f(FF[mi_][2].z), bf2f(FF[mi_][2].w)}; \
        c0_ = __builtin_amdgcn_mfma_f32_16x16x32_bf16(afrag[mi_], BF[0], c0_, 0, 0, 0); \
        c1_ = __builtin_amdgcn_mfma_f32_16x16x32_bf16(afrag[mi_], BF[1], c1_, 0, 0, 0); \
        c2_ = __builtin_amdgcn_mfma_f32_16x16x32_bf16(afrag[mi_], BF[2], c2_, 0, 0, 0); \
        _Pragma("unroll")                                                            \
        for (int r_ = 0; r_ < 4; ++r_) {                                             \
            float v0_ = c0_[r_], v1_ = c1_[r_], v2_ = c2_[r_];                       \
            float mm_ = fmaxf(fmaxf(v0_, v1_), v2_);                                 \
            mm_ = fmaxf(mm_, __shfl_xor(mm_, 1, 16));                                \
            mm_ = fmaxf(mm_, __shfl_xor(mm_, 2, 16));                                \
            mm_ = fmaxf(mm_, __shfl_xor(mm_, 4, 16));                                \
            mm_ = fmaxf(mm_, __shfl_xor(mm_, 8, 16));                                \
            float mn_ = fmaxf(rm[mi_][r_], mm_);                                     \
            float a_ = __expf(rm[mi_][r_] - mn_);                                    \
            float s0_ = __expf(v0_ - mn_), s1_ = __expf(v1_ - mn_), s2_ = __expf(v2_ - mn_); \
            float ss_ = s0_ + s1_ + s2_;                                             \
            ss_ += __shfl_xor(ss_, 1, 16);                                           \
            ss_ += __shfl_xor(ss_, 2, 16);                                           \
            ss_ += __shfl_xor(ss_, 4, 16);                                           \
            ss_ += __shfl_xor(ss_, 8, 16);                                           \
            rl[mi_][r_] = rl[mi_][r_] * a_ + ss_;                                    \
            rm[mi_][r_] = mn_;                                                       \
            acc[mi_][0][r_] *= a_; acc[mi_][1][r_] *= a_;                            \
            acc[mi_][2][r_] *= a_; acc[mi_][3][r_] *= a_;                            \
            int rw_ = mi_ * 16 + quad * 4 + r_;                                      \
            Pp[rw_ * 56 +      n16] = f2bf(s0_);                                     \
            Pp[rw_ * 56 + 16 + n16] = f2bf(s1_);                                     \
            Pp[rw_ * 56 + 32 + n16] = f2bf(s2_);                                     \
        }                                                                            \
    }                                                                                \
    _Pragma("unroll")                                                                \
    for (int kk_ = 0; kk_ < 2; ++kk_) {                                              \
        bf16x8 Bv_[4];                                                               \
        _Pragma("unroll")                                                            \
        for (int ct_ = 0; ct_ < 4; ++ct_) {                                          \
            int c_ = ct_ * 16 + n16;                                                 \
            int bp_ = ((kk_ * 4 + quad) ^ (c_ >> 3) ^ (((c_ >> 2) & 1) << 2)) & 7;   \
            Bv_[ct_] = *(const bf16x8*)(Vw + c_ * 64 + bp_ * 8);                     \
        }                                                                            \
        _Pragma("unroll")                                                            \
        for (int mi_ = 0; mi_ < 3; ++mi_) {                                          \
            if (mi_ >= nmt) continue;                                                \
            bf16x8 Ap_ = {};                                                         \
            if (kk_ == 0)                                                            \
                Ap_ = *(const bf16x8*)(Pp + (mi_ * 16 + n16) * 56 + quad * 8);       \
            else if (quad < 2)                                                       \
                Ap_ = *(const bf16x8*)(Pp + (mi_ * 16 + n16) * 56 + 32 + quad * 8);  \
            _Pragma("unroll")                                                        \
            for (int ct_ = 0; ct_ < 4; ++ct_)                                        \
                acc[mi_][ct_] = __builtin_amdgcn_mfma_f32_16x16x32_bf16(Ap_, Bv_[ct_], acc[mi_][ct_], 0, 0, 0); \
        }                                                                            \
    }                                                                                \
} while (0)

    ATTN_LOAD(0, vaA, vbA, bfA, fA);
    for (int T2 = 0; T2 < 8; T2 += 2) {
        ATTN_ITER(T2,     vaA, vbA, bfA, fA, vaB, vbB, bfB, fB);
        ATTN_ITER(T2 + 1, vaB, vbB, bfB, fB, vaA, vbA, bfA, fA);
    }
    ATTN_ITER(8, vaA, vbA, bfA, fA, vaB, vbB, bfB, fB);

#undef ATTN_ITER
#undef ATTN_LOAD

    // ---- epilogue: bsc + normalized scatter of ret (wave-local rows, all ch) ----
    if (n16 == 0) {
        #pragma unroll
        for (int mi = 0; mi < 3; ++mi) {
            if (mi >= nmt) continue;
            int mt = wv + mi * 4;
            #pragma unroll
            for (int r = 0; r < 4; ++r)
                bsc[((size_t)n * 4 + h) * LL + t_arr[mt * 16 + quad * 4 + r]] =
                    rm[mi][r] + __logf(rl[mi][r]);
        }
    }
    size_t obase = ((size_t)n * 4 + h) * LL;
    #pragma unroll
    for (int mi = 0; mi < 3; ++mi) {
        if (mi >= nmt) continue;
        int mt = wv + mi * 4;
        #pragma unroll
        for (int r = 0; r < 4; ++r) {
            int t = t_arr[mt * 16 + quad * 4 + r];
            float inv = 1.f / rl[mi][r];
            #pragma unroll
            for (int ct = 0; ct < 4; ++ct)
                ret[(obase + t) * 64 + ct * 16 + n16] = f2bf(acc[mi][ct][r] * inv);
        }
    }
}

// ---------------- K5: softmax over rounds + residual, NCHW output ----------------
__global__ __launch_bounds__(256) void k_final(
    const unsigned short* __restrict__ ret, const float* __restrict__ bsc,
    const float* __restrict__ x, float* __restrict__ out)
{
    __shared__ float pr[4][64];
    __shared__ float accl[64 * 65];
    int b = blockIdx.x, n = b / 144;
    int t0 = (b % 144) * 64;
    int tid = threadIdx.x;
    if (tid < 64) {
        int t = t0 + tid;
        float b0 = bsc[((size_t)n*4 + 0)*LL + t];
        float b1 = bsc[((size_t)n*4 + 1)*LL + t];
        float b2 = bsc[((size_t)n*4 + 2)*LL + t];
        float b3 = bsc[((size_t)n*4 + 3)*LL + t];
        float mx = fmaxf(fmaxf(b0, b1), fmaxf(b2, b3));
        float e0 = __expf(b0-mx), e1 = __expf(b1-mx), e2 = __expf(b2-mx), e3 = __expf(b3-mx);
        float inv = 1.f / (e0 + e1 + e2 + e3);
        pr[0][tid] = e0*inv; pr[1][tid] = e1*inv; pr[2][tid] = e2*inv; pr[3][tid] = e3*inv;
    }
    __syncthreads();
    int cc = tid & 63, tt4 = tid >> 6;
    #pragma unroll
    for (int q = 0; q < 16; ++q) {
        int tt = tt4 + 4*q;
        int t = t0 + tt;
        float v = 0.f;
        #pragma unroll
        for (int h2 = 0; h2 < 4; ++h2)
            v += bf2f(ret[(((size_t)n*4 + h2)*LL + t)*64 + cc]) * pr[h2][tt];
        accl[cc*65 + tt] = v;
    }
    __syncthreads();
    int tt = tid & 63, c4 = tid >> 6;
    #pragma unroll
    for (int q = 0; q < 16; ++q) {
        int ch = c4 + 4*q;
        size_t o = ((size_t)n*64 + ch)*LL + t0 + tt;
        out[o] = accl[ch*65 + tt] + x[o];   // RES_SCALE = 1.0
    }
}

// ---------------- launcher ----------------
extern "C" void kernel_launch(void* const* d_in, const int* in_sizes, int n_in,
                              void* d_out, int out_size, void* d_ws, size_t ws_size,
                              hipStream_t stream)
{
    const float* x    = (const float*)d_in[0];
    const float* rot  = (const float*)d_in[1];
    const float* wm   = (const float*)d_in[2];
    const float* bm   = (const float*)d_in[3];
    const float* wa   = (const float*)d_in[4];
    const float* ba   = (const float*)d_in[5];
    const float* wf   = (const float*)d_in[6];
    const float* bf   = (const float*)d_in[7];
    const float* fc1w = (const float*)d_in[8];
    const float* fc1b = (const float*)d_in[9];
    const float* fc2w = (const float*)d_in[10];
    const float* fc2b = (const float*)d_in[11];
    float* out = (float*)d_out;

    char* ws = (char*)d_ws;
    unsigned short* xeb  = (unsigned short*)(ws + 0);         // 2*9216*16 bf16
    unsigned short* yeb  = (unsigned short*)(ws + 589824);    // 2*9216*64 bf16
    unsigned short* xnb  = (unsigned short*)(ws + 2949120);   // 2*9216*16 bf16
    unsigned short* re2b = (unsigned short*)(ws + 3538944);   // 2*9216*144 bf16
    unsigned short* w1bf = (unsigned short*)(ws + 8847360);   // 144*64 bf16
    unsigned short* w2bf = (unsigned short*)(ws + 8865792);   // 144*160 bf16
    unsigned short* wpak = (unsigned short*)(ws + 8911872);   // 128*576 bf16
    unsigned char* codes = (unsigned char*)(ws + 9059328);    // 2*36864 u8
    int* hist            = (int*)(ws + 9133056);              // 2*256*144 i32
    int* idxb            = (int*)(ws + 9427968);              // 2*36864 i32
    unsigned short* retb = (unsigned short*)(ws + 9575424);   // 2*4*9216*64 bf16
    float* bscb          = (float*)(ws + 19012608);           // 2*4*9216 f32 (end 19,307,520)

    k_front    <<<576, 256, 0, stream>>>(x, wm, bm, rot, xeb, xnb, codes,
                                         fc1w, fc2w, wa, wf, w1bf, w2bf, wpak);
    k_convbf_fc<<<672, 256, 0, stream>>>(x, wpak, ba, bf, w1bf, fc1b, w2bf, fc2b,
                                         yeb, re2b, codes, hist);
    k_scan     <<<2,   256, 0, stream>>>(hist);
    k_place    <<<288, 256, 0, stream>>>(codes, hist, idxb);
    k_attn     <<<512, 256, 0, stream>>>(xeb, xnb, yeb, re2b, idxb, retb, bscb);
    k_final    <<<288, 256, 0, stream>>>(retb, bscb, x, out);
}